// Round 10
// baseline (1924.970 us; speedup 1.0000x reference)
//
#include <hip/hip_runtime.h>
#include <hip/hip_bf16.h>

#define T_   64
#define N_   50000
#define E_   1600000
#define GH_  32
#define RH_  64
#define TB_  8                     // timesteps per pass
#define NP_  (T_ / TB_)            // 8 passes
#define XB_  3125                  // gather blocks: cdiv(N*8,256)
#define GB_  782                   // gru blocks: cdiv(N,64)
#define NB_  196                   // node blocks: cdiv(N,256)
#define AB_  12500                 // aall blocks: cdiv(N*64,256)

typedef _Float16 half_t;
typedef __attribute__((ext_vector_type(8))) _Float16 half8;
typedef __attribute__((ext_vector_type(4))) float f32x4;

static __device__ __forceinline__ float fast_sigmoid(float v) {
    float e = __expf(-v);
    return __builtin_amdgcn_rcpf(1.0f + e);
}
static __device__ __forceinline__ float fast_tanh(float v) {
    return 2.0f * fast_sigmoid(2.0f * v) - 1.0f;
}

// ---------- prologue ----------

// dyn [T,N] fp32 -> dynT [N,T] fp16
__global__ __launch_bounds__(256)
void k_transpose(const float* __restrict__ dyn, half_t* __restrict__ dynT) {
    __shared__ float tile[64][65];
    int n0 = blockIdx.x * 64;
    int tx = threadIdx.x, ty = threadIdx.y;
#pragma unroll
    for (int r = 0; r < 16; ++r) {
        int t = r * 4 + ty;
        int n = n0 + tx;
        tile[t][tx] = (n < N_) ? dyn[(size_t)t * N_ + n] : 0.0f;
    }
    __syncthreads();
#pragma unroll
    for (int r = 0; r < 16; ++r) {
        int nl = r * 4 + ty;
        int n = n0 + nl;
        if (n < N_) dynT[(size_t)n * 64 + tx] = (half_t)tile[tx][nl];
    }
}

// per-(dst, src-tile) histogram
__global__ void k_hist(const int* __restrict__ src, const int* __restrict__ dst,
                       int* __restrict__ cnt) {
    int e = blockIdx.x * blockDim.x + threadIdx.x;
    if (e >= E_) return;
    atomicAdd(&cnt[dst[e] * 16 + (src[e] >> 12)], 1);
}

// deg from cnt + per-block inclusive scan
__global__ __launch_bounds__(256)
void k_scanA(const int* __restrict__ cnt, int* __restrict__ deg,
             int* __restrict__ row_ptr, int* __restrict__ bsum) {
    __shared__ int buf[256];
    int tid = threadIdx.x;
    int i = blockIdx.x * 256 + tid;
    int v = 0;
    if (i < N_) {
        const int4* c4 = (const int4*)(cnt + i * 16);
#pragma unroll
        for (int c = 0; c < 4; ++c) {
            int4 w = c4[c];
            v += w.x + w.y + w.z + w.w;
        }
        deg[i] = v;
    }
    buf[tid] = v;
    __syncthreads();
#pragma unroll
    for (int off = 1; off < 256; off <<= 1) {
        int t = (tid >= off) ? buf[tid - off] : 0;
        __syncthreads();
        buf[tid] += t;
        __syncthreads();
    }
    if (i < N_) row_ptr[i + 1] = buf[tid];
    if (tid == 255) bsum[blockIdx.x] = buf[255];
}
__global__ __launch_bounds__(256)
void k_scanB(int* __restrict__ bsum, int nb) {
    __shared__ int buf[256];
    int tid = threadIdx.x;
    buf[tid] = (tid < nb) ? bsum[tid] : 0;
    __syncthreads();
#pragma unroll
    for (int off = 1; off < 256; off <<= 1) {
        int t = (tid >= off) ? buf[tid - off] : 0;
        __syncthreads();
        buf[tid] += t;
        __syncthreads();
    }
    if (tid < nb) bsum[tid] = (tid > 0) ? buf[tid - 1] : 0;
}
__global__ __launch_bounds__(256)
void k_scanC(int* __restrict__ row_ptr, const int* __restrict__ bsum) {
    int i = blockIdx.x * 256 + threadIdx.x;
    if (i == 0) row_ptr[0] = 0;
    if (i < N_) row_ptr[i + 1] += bsum[blockIdx.x];
}

// rp2[n][t] = row_ptr[n] + prefix(cnt[n][0..t)); zero cnt (reused as cursor)
__global__ __launch_bounds__(256)
void k_rowscan(const int* __restrict__ row_ptr, int* __restrict__ cnt,
               int* __restrict__ rp2) {
    int n = blockIdx.x * 256 + threadIdx.x;
    if (n >= N_) return;
    int run = row_ptr[n];
#pragma unroll
    for (int t = 0; t < 16; ++t) {
        int c = cnt[n * 16 + t];
        rp2[n * 16 + t] = run;
        run += c;
        cnt[n * 16 + t] = 0;
    }
}

__global__ __launch_bounds__(256)
void k_node_init(const int* __restrict__ deg,
                 const float* __restrict__ statics,
                 const float* __restrict__ w0,
                 float* __restrict__ dinv,
                 float* __restrict__ selfn,
                 half_t* __restrict__ h0s) {          // [N,32] f16
    int n = blockIdx.x * blockDim.x + threadIdx.x;
    if (n >= N_) return;
    float d  = (float)deg[n] + 1.0f;
    float di = rsqrtf(d);
    dinv[n] = di;
    selfn[n] = di * di;
    float s[6];
#pragma unroll
    for (int j = 0; j < 6; ++j) s[j] = statics[n * 6 + j];
    half8 o[4];
#pragma unroll
    for (int k = 0; k < GH_; ++k) {
        float v = 0.0f;
#pragma unroll
        for (int j = 0; j < 6; ++j) v += s[j] * w0[(1 + j) * GH_ + k];
        o[k >> 3][k & 7] = (half_t)v;
    }
    half8* dst8 = (half8*)(h0s + (size_t)n * GH_);
#pragma unroll
    for (int c = 0; c < 4; ++c) dst8[c] = o[c];
}

// tile-ordered scatter: 8-byte record {src, norm}
__global__ void k_scatter2(const int* __restrict__ src, const int* __restrict__ dst,
                           const float* __restrict__ dinv,
                           const int* __restrict__ rp2, int* __restrict__ cnt,
                           int2* __restrict__ erec) {
    int e = blockIdx.x * blockDim.x + threadIdx.x;
    if (e >= E_) return;
    int s = src[e], d = dst[e];
    int slot = d * 16 + (s >> 12);
    int pos = rp2[slot] + atomicAdd(&cnt[slot], 1);
    erec[pos] = make_int2(s, __float_as_int(dinv[s] * dinv[d]));
}

// pre-swizzled GRU weight fragments, f16.
// layout: wB[(((c*12+nt)*4+q)*16+m)*8+j] = wT[k=c*32+q*8+j][col=nt*16+m]
__global__ void k_wB(const float* __restrict__ wih, const float* __restrict__ whh,
                     half_t* __restrict__ wB) {
    int idx = blockIdx.x * 256 + threadIdx.x;
    if (idx >= 96 * 192) return;
    int j = idx & 7;
    int r = idx >> 3;
    int m = r & 15; r >>= 4;
    int q = r & 3;  r >>= 2;
    int nt = r % 12;
    int c = r / 12;
    int k = c * 32 + q * 8 + j;
    int col = nt * 16 + m;
    float v = (k < 32) ? wih[col * 32 + k] : whh[col * 64 + (k - 32)];
    wB[idx] = (half_t)v;
}

// ---------- fused aall + csagg gather ----------

static __device__ __forceinline__
void aall_body(int bid, const int* __restrict__ row_ptr, const int2* __restrict__ erec,
               const float* __restrict__ selfn, const half_t* __restrict__ dynT,
               float* __restrict__ aT) {
    int gid = bid * 256 + threadIdx.x;
    int n = gid >> 6, lane = gid & 63;
    if (n >= N_) return;
    float acc = selfn[n] * (float)dynT[(size_t)n * 64 + lane];
    int e0 = row_ptr[n], e1 = row_ptr[n + 1];
    int e = e0;
    for (; e < e1 && (e & 3); ++e) {
        int2 r = erec[e];
        acc += __int_as_float(r.y) * (float)dynT[(size_t)r.x * 64 + lane];
    }
    for (; e + 4 <= e1; e += 4) {
        int4 p0 = *(const int4*)(erec + e);
        int4 p1 = *(const int4*)(erec + e + 2);
        float v0 = (float)dynT[(size_t)p0.x * 64 + lane];
        float v1 = (float)dynT[(size_t)p0.z * 64 + lane];
        float v2 = (float)dynT[(size_t)p1.x * 64 + lane];
        float v3 = (float)dynT[(size_t)p1.z * 64 + lane];
        acc += __int_as_float(p0.y) * v0 + __int_as_float(p0.w) * v1
             + __int_as_float(p1.y) * v2 + __int_as_float(p1.w) * v3;
    }
    for (; e < e1; ++e) {
        int2 r = erec[e];
        acc += __int_as_float(r.y) * (float)dynT[(size_t)r.x * 64 + lane];
    }
    aT[(size_t)n * 64 + lane] = acc;
}

static __device__ __forceinline__
void g16s_body(int bid, const int* __restrict__ row_ptr, const int2* __restrict__ erec,
               const float* __restrict__ selfn, const half_t* __restrict__ h0s,
               float* __restrict__ csagg) {
    int gid = bid * 256 + threadIdx.x;
    int n = gid >> 2, q = gid & 3;
    if (n >= N_) return;
    const half8* f8 = (const half8*)h0s;
    float acc[8];
    {
        half8 sv = f8[(size_t)n * 4 + q];
        float sn = selfn[n];
#pragma unroll
        for (int i = 0; i < 8; ++i) acc[i] = sn * (float)sv[i];
    }
    int e0 = row_ptr[n], e1 = row_ptr[n + 1];
    int e = e0;
    for (; e < e1 && (e & 3); ++e) {
        int2 r = erec[e];
        float nm = __int_as_float(r.y);
        half8 v = f8[(size_t)r.x * 4 + q];
#pragma unroll
        for (int i = 0; i < 8; ++i) acc[i] += nm * (float)v[i];
    }
    for (; e + 4 <= e1; e += 4) {
        int4 p0 = *(const int4*)(erec + e);
        int4 p1 = *(const int4*)(erec + e + 2);
        half8 v0 = f8[(size_t)p0.x * 4 + q];
        half8 v1 = f8[(size_t)p0.z * 4 + q];
        half8 v2 = f8[(size_t)p1.x * 4 + q];
        half8 v3 = f8[(size_t)p1.z * 4 + q];
        float n0 = __int_as_float(p0.y), n1 = __int_as_float(p0.w);
        float n2 = __int_as_float(p1.y), n3 = __int_as_float(p1.w);
#pragma unroll
        for (int i = 0; i < 8; ++i)
            acc[i] += n0 * (float)v0[i] + n1 * (float)v1[i]
                    + n2 * (float)v2[i] + n3 * (float)v3[i];
    }
    for (; e < e1; ++e) {
        int2 r = erec[e];
        float nm = __int_as_float(r.y);
        half8 v = f8[(size_t)r.x * 4 + q];
#pragma unroll
        for (int i = 0; i < 8; ++i) acc[i] += nm * (float)v[i];
    }
    float4* out = (float4*)(csagg + (size_t)n * GH_ + q * 8);
    out[0] = make_float4(acc[0], acc[1], acc[2], acc[3]);
    out[1] = make_float4(acc[4], acc[5], acc[6], acc[7]);
}

__global__ __launch_bounds__(256)
void k_aux(const int* __restrict__ row_ptr, const int2* __restrict__ erec,
           const float* __restrict__ selfn, const half_t* __restrict__ dynT,
           float* __restrict__ aT, const half_t* __restrict__ h0s,
           float* __restrict__ csagg) {
    if ((int)blockIdx.x < AB_)
        aall_body(blockIdx.x, row_ptr, erec, selfn, dynT, aT);
    else
        g16s_body((int)blockIdx.x - AB_, row_ptr, erec, selfn, h0s, csagg);
}

// ---------- per-pass ----------

// g1blk[n][u][32] f16 for u = 0..7 (t = tb+u)
static __device__ __forceinline__
void g1_body(int bid, int tb, const float* __restrict__ aT,
             const float* __restrict__ csagg, const float* __restrict__ w0,
             const float* __restrict__ b0, const float* __restrict__ w1,
             half_t* __restrict__ g1blk) {
    int n = bid * 256 + threadIdx.x;
    if (n >= N_) return;
    float c[GH_];
#pragma unroll
    for (int k = 0; k < GH_; ++k) c[k] = csagg[(size_t)n * GH_ + k] + b0[k];
    const float* at = aT + (size_t)n * 64 + tb;
    half8* outp = (half8*)(g1blk + (size_t)n * (TB_ * GH_));
#pragma unroll 1
    for (int u = 0; u < TB_; ++u) {
        float av = at[u];
        float h1[GH_];
#pragma unroll
        for (int k = 0; k < GH_; ++k) {
            float v = av * w0[k] + c[k];
            h1[k] = v > 0.0f ? v : 0.0f;
        }
        half8 o[4];
#pragma unroll
        for (int j = 0; j < GH_; ++j) {
            float v = 0.0f;
#pragma unroll
            for (int k = 0; k < GH_; ++k) v += h1[k] * w1[k * GH_ + j];
            o[j >> 3][j & 7] = (half_t)v;
        }
#pragma unroll
        for (int cc = 0; cc < 4; ++cc) outp[u * 4 + cc] = o[cc];
    }
}

__global__ __launch_bounds__(256)
void k_g1blk(const float* __restrict__ aT, const float* __restrict__ csagg,
             const float* __restrict__ w0, const float* __restrict__ b0,
             const float* __restrict__ w1, half_t* __restrict__ g1blk, int tb) {
    g1_body(blockIdx.x, tb, aT, csagg, w0, b0, w1, g1blk);
}

// fused: gather(p) on blocks [0,XB): 8 lanes/node, 512B/edge, g1cur -> xblk
//        g1(p+1) on blocks [XB, XB+NB): aT -> g1nxt
__global__ __launch_bounds__(256)
void k_gather_g1(const int* __restrict__ row_ptr, const int2* __restrict__ erec,
                 const float* __restrict__ selfn, const half_t* __restrict__ g1cur,
                 const float* __restrict__ b1, half_t* __restrict__ xblk,
                 const float* __restrict__ aT, const float* __restrict__ csagg,
                 const float* __restrict__ w0, const float* __restrict__ b0,
                 const float* __restrict__ w1, half_t* __restrict__ g1nxt,
                 int tb_next, int do_g1) {
    if ((int)blockIdx.x >= XB_) {
        if (do_g1)
            g1_body((int)blockIdx.x - XB_, tb_next, aT, csagg, w0, b0, w1, g1nxt);
        return;
    }
    int gid = blockIdx.x * 256 + threadIdx.x;
    int n = gid >> 3, q = gid & 7;
    if (n >= N_) return;
    const half8* g8 = (const half8*)g1cur;   // node row = 32 chunks of 16B
    float acc[4][8];
    {
        float sn = selfn[n];
#pragma unroll
        for (int u = 0; u < 4; ++u) {
            half8 sv = g8[(size_t)n * 32 + q + 8 * u];
#pragma unroll
            for (int i = 0; i < 8; ++i) acc[u][i] = sn * (float)sv[i];
        }
    }
    int e0 = row_ptr[n], e1 = row_ptr[n + 1];
    int e = e0;
    for (; e < e1 && (e & 3); ++e) {
        int2 r = erec[e];
        float nm = __int_as_float(r.y);
        size_t base = (size_t)r.x * 32 + q;
#pragma unroll
        for (int u = 0; u < 4; ++u) {
            half8 v = g8[base + 8 * u];
#pragma unroll
            for (int i = 0; i < 8; ++i) acc[u][i] += nm * (float)v[i];
        }
    }
    for (; e + 4 <= e1; e += 4) {
        int4 p0 = *(const int4*)(erec + e);
        int4 p1 = *(const int4*)(erec + e + 2);
        size_t b0a = (size_t)p0.x * 32 + q;
        size_t b1a = (size_t)p0.z * 32 + q;
        size_t b2a = (size_t)p1.x * 32 + q;
        size_t b3a = (size_t)p1.z * 32 + q;
        float n0 = __int_as_float(p0.y), n1 = __int_as_float(p0.w);
        float n2 = __int_as_float(p1.y), n3 = __int_as_float(p1.w);
        half8 v0[4], v1[4], v2[4], v3[4];
#pragma unroll
        for (int u = 0; u < 4; ++u) {
            v0[u] = g8[b0a + 8 * u];
            v1[u] = g8[b1a + 8 * u];
            v2[u] = g8[b2a + 8 * u];
            v3[u] = g8[b3a + 8 * u];
        }
#pragma unroll
        for (int u = 0; u < 4; ++u)
#pragma unroll
            for (int i = 0; i < 8; ++i)
                acc[u][i] += n0 * (float)v0[u][i] + n1 * (float)v1[u][i]
                           + n2 * (float)v2[u][i] + n3 * (float)v3[u][i];
    }
    for (; e < e1; ++e) {
        int2 r = erec[e];
        float nm = __int_as_float(r.y);
        size_t base = (size_t)r.x * 32 + q;
#pragma unroll
        for (int u = 0; u < 4; ++u) {
            half8 v = g8[base + 8 * u];
#pragma unroll
            for (int i = 0; i < 8; ++i) acc[u][i] += nm * (float)v[i];
        }
    }
    int kc = (q & 3) * 8;
    const float* bb = b1 + kc;
#pragma unroll
    for (int u = 0; u < 4; ++u) {
        int t = (q >> 2) + 2 * u;
        half8 o;
#pragma unroll
        for (int i = 0; i < 8; ++i)
            o[i] = (half_t)fmaxf(acc[u][i] + bb[i], 0.0f);
        *(half8*)(xblk + ((size_t)t * N_ + n) * GH_ + kc) = o;
    }
}

// ---------- MFMA GRU: 8 timesteps, h in LDS f16, weights direct from wB ----------
#define HSTR_ 72
__global__ __launch_bounds__(256, 2)
void k_gruMM(const half_t* __restrict__ xblk,   // [TB][N][32] f16
             const half_t* __restrict__ wB,     // swizzled fragments
             const float* __restrict__ bih, const float* __restrict__ bhh,
             half_t* __restrict__ hA) {         // [Npad][64] f16
    __shared__ half_t hL[64 * HSTR_];
    int tid = threadIdx.x;
    int nb0 = blockIdx.x * 64;
    for (int i = tid; i < 64 * 8; i += 256) {
        int node = i >> 3, ch = i & 7;
        half8 v = *(const half8*)(hA + (size_t)(nb0 + node) * RH_ + ch * 8);
        *(half8*)(hL + node * HSTR_ + ch * 8) = v;
    }
    __syncthreads();
    int lane = tid & 63;
    int wv = tid >> 6;
    int c16 = lane & 15, q = lane >> 4;
    const half8* wB8 = (const half8*)wB;
    half8 bfr[3][12];
#pragma unroll
    for (int c = 0; c < 3; ++c)
#pragma unroll
        for (int nt = 0; nt < 12; ++nt)
            bfr[c][nt] = wB8[((c * 12 + nt) * 4 + q) * 16 + c16];
    float br[4], bz[4], bnx[4], bnh[4];
#pragma unroll
    for (int jt = 0; jt < 4; ++jt) {
        int j = jt * 16 + c16;
        br[jt]  = bih[j] + bhh[j];
        bz[jt]  = bih[64 + j] + bhh[64 + j];
        bnx[jt] = bih[128 + j];
        bnh[jt] = bhh[128 + j];
    }
    int mrow = wv * 16 + c16;
    const half_t* hrow = hL + mrow * HSTR_;
    const f32x4 zero = {0.0f, 0.0f, 0.0f, 0.0f};
#pragma unroll 1
    for (int u = 0; u < TB_; ++u) {
        half8 ax  = *(const half8*)(xblk + ((size_t)u * N_ + nb0 + mrow) * GH_ + q * 8);
        half8 ah0 = *(const half8*)(hrow + q * 8);
        half8 ah1 = *(const half8*)(hrow + 32 + q * 8);
        f32x4 Crz[8], Cnx[4], Cnh[4];
#pragma unroll
        for (int nt = 0; nt < 8; ++nt) {
            Crz[nt] = __builtin_amdgcn_mfma_f32_16x16x32_f16(ax,  bfr[0][nt], zero,     0, 0, 0);
            Crz[nt] = __builtin_amdgcn_mfma_f32_16x16x32_f16(ah0, bfr[1][nt], Crz[nt], 0, 0, 0);
            Crz[nt] = __builtin_amdgcn_mfma_f32_16x16x32_f16(ah1, bfr[2][nt], Crz[nt], 0, 0, 0);
        }
#pragma unroll
        for (int nt = 0; nt < 4; ++nt) {
            Cnx[nt] = __builtin_amdgcn_mfma_f32_16x16x32_f16(ax,  bfr[0][8 + nt], zero,     0, 0, 0);
            Cnh[nt] = __builtin_amdgcn_mfma_f32_16x16x32_f16(ah0, bfr[1][8 + nt], zero,     0, 0, 0);
            Cnh[nt] = __builtin_amdgcn_mfma_f32_16x16x32_f16(ah1, bfr[2][8 + nt], Cnh[nt], 0, 0, 0);
        }
#pragma unroll
        for (int jt = 0; jt < 4; ++jt) {
#pragma unroll
            for (int reg = 0; reg < 4; ++reg) {
                int nl = wv * 16 + q * 4 + reg;
                int jj = jt * 16 + c16;
                float hold = (float)hL[nl * HSTR_ + jj];
                float r  = fast_sigmoid(Crz[jt][reg] + br[jt]);
                float z  = fast_sigmoid(Crz[4 + jt][reg] + bz[jt]);
                float cd = fast_tanh(Cnx[jt][reg] + bnx[jt] + r * (Cnh[jt][reg] + bnh[jt]));
                hL[nl * HSTR_ + jj] = (half_t)((1.0f - z) * cd + z * hold);
            }
        }
    }
    __syncthreads();
    for (int i = tid; i < 64 * 8; i += 256) {
        int node = i >> 3, ch = i & 7;
        half8 v = *(const half8*)(hL + node * HSTR_ + ch * 8);
        *(half8*)(hA + (size_t)(nb0 + node) * RH_ + ch * 8) = v;
    }
}

__global__ __launch_bounds__(256)
void k_mlp(const half_t* __restrict__ hA, const float* __restrict__ w1,
           const float* __restrict__ b1, const float* __restrict__ w2,
           const float* __restrict__ b2, float* __restrict__ out) {
    int n = blockIdx.x * blockDim.x + threadIdx.x;
    if (n >= N_) return;
    float h[RH_];
    const half8* h8 = (const half8*)(hA + (size_t)n * RH_);
#pragma unroll
    for (int c = 0; c < 8; ++c) {
        half8 v = h8[c];
#pragma unroll
        for (int i = 0; i < 8; ++i) h[c * 8 + i] = (float)v[i];
    }
    float acc = b2[0];
#pragma unroll 1
    for (int j = 0; j < RH_; ++j) {
        float v = b1[j];
#pragma unroll
        for (int k = 0; k < RH_; ++k) v += w1[j * RH_ + k] * h[k];
        v = v > 0.0f ? v : 0.0f;
        acc += w2[j] * v;
    }
    out[n] = acc;
}

extern "C" void kernel_launch(void* const* d_in, const int* in_sizes, int n_in,
                              void* d_out, int out_size, void* d_ws, size_t ws_size,
                              hipStream_t stream) {
    const float* dyn     = (const float*)d_in[0];
    const float* statics = (const float*)d_in[1];
    const int*   ei      = (const int*)d_in[2];
    const float* w0      = (const float*)d_in[3];
    const float* b0      = (const float*)d_in[4];
    const float* w1      = (const float*)d_in[5];
    const float* b1      = (const float*)d_in[6];
    const float* wih     = (const float*)d_in[7];
    const float* whh     = (const float*)d_in[8];
    const float* bih     = (const float*)d_in[9];
    const float* bhh     = (const float*)d_in[10];
    const float* mw1     = (const float*)d_in[11];
    const float* mb1     = (const float*)d_in[12];
    const float* mw2     = (const float*)d_in[13];
    const float* mb2     = (const float*)d_in[14];
    const int* src = ei;
    const int* dst = ei + E_;

    char* ws = (char*)d_ws;
    auto alloc = [&](size_t elems) {        // 4B units, 256B-aligned
        elems = (elems + 63) & ~(size_t)63;
        void* p = ws; ws += elems * 4; return p;
    };
    const int NPAD = N_ + 64;
    int*    deg     = (int*)alloc(N_);
    int*    row_ptr = (int*)alloc(N_ + 4);
    int*    bsum    = (int*)alloc(256);
    int*    cnt     = (int*)alloc((size_t)N_ * 16);
    int*    rp2     = (int*)alloc((size_t)N_ * 16);
    int2*   erec    = (int2*)alloc((size_t)E_ * 2);
    float*  dinv    = (float*)alloc(N_);
    float*  selfn   = (float*)alloc(N_);
    half_t* h0s     = (half_t*)alloc((size_t)N_ * GH_ / 2);        // f16 [N,32]
    float*  csagg   = (float*)alloc(32 * N_);
    half_t* g1b0    = (half_t*)alloc((size_t)N_ * TB_ * GH_ / 2);  // f16 [N][8][32]
    half_t* g1b1    = (half_t*)alloc((size_t)N_ * TB_ * GH_ / 2);
    half_t* xblk    = (half_t*)alloc(((size_t)TB_ * N_ + 64) * GH_ / 2); // f16 [8][N][32]
    half_t* hA      = (half_t*)alloc((size_t)NPAD * RH_ / 2);      // f16 [Npad][64]
    half_t* dynT    = (half_t*)alloc((size_t)N_ * 64 / 2);         // f16 [N][64]
    float*  aT      = (float*)alloc(64 * N_);
    half_t* wB      = (half_t*)alloc(96 * 192 / 2);

    auto cdiv = [](long long x, int b) { return (unsigned)((x + b - 1) / b); };
    const int B = 256;

    hipMemsetAsync(cnt, 0, (size_t)N_ * 16 * sizeof(int), stream);
    hipMemsetAsync(hA, 0, (size_t)NPAD * RH_ * sizeof(half_t), stream);

    k_transpose<<<cdiv(N_, 64), dim3(64, 4), 0, stream>>>(dyn, dynT);
    k_hist<<<cdiv(E_, B), B, 0, stream>>>(src, dst, cnt);
    k_scanA<<<NB_, B, 0, stream>>>(cnt, deg, row_ptr, bsum);
    k_scanB<<<1, B, 0, stream>>>(bsum, NB_);
    k_scanC<<<NB_, B, 0, stream>>>(row_ptr, bsum);
    k_rowscan<<<NB_, B, 0, stream>>>(row_ptr, cnt, rp2);
    k_node_init<<<NB_, B, 0, stream>>>(deg, statics, w0, dinv, selfn, h0s);
    k_scatter2<<<cdiv(E_, B), B, 0, stream>>>(src, dst, dinv, rp2, cnt, erec);
    k_wB<<<cdiv(96 * 192, B), B, 0, stream>>>(wih, whh, wB);
    k_aux<<<AB_ + GB_, B, 0, stream>>>(row_ptr, erec, selfn, dynT, aT, h0s, csagg);

    k_g1blk<<<NB_, B, 0, stream>>>(aT, csagg, w0, b0, w1, g1b0, 0);
    for (int p = 0; p < NP_; ++p) {
        half_t* cur = (p & 1) ? g1b1 : g1b0;
        half_t* nxt = (p & 1) ? g1b0 : g1b1;
        int do_g1 = (p + 1 < NP_) ? 1 : 0;
        unsigned grid = XB_ + (do_g1 ? NB_ : 0);
        k_gather_g1<<<grid, B, 0, stream>>>(row_ptr, erec, selfn, cur, b1, xblk,
                                            aT, csagg, w0, b0, w1, nxt,
                                            (p + 1) * TB_, do_g1);
        k_gruMM<<<GB_, B, 0, stream>>>(xblk, wB, bih, bhh, hA);
    }
    k_mlp<<<NB_, B, 0, stream>>>(hA, mw1, mb1, mw2, mb2, (float*)d_out);
}

// Round 12
// 1814.561 us; speedup vs baseline: 1.0608x; 1.0608x over previous
//
#include <hip/hip_runtime.h>
#include <hip/hip_bf16.h>

#define T_   64
#define N_   50000
#define E_   1600000
#define GH_  32
#define RH_  64
#define TB_  16                    // timesteps per pass
#define NP_  (T_ / TB_)            // 4 passes
#define XB_  3125                  // gather blocks: cdiv(N*16,256)
#define GB_  782                   // gru blocks: cdiv(N,64)
#define NB_  196                   // node blocks: cdiv(N,256)
#define AB_  12500                 // aall blocks: cdiv(N*64,256)

typedef _Float16 half_t;
typedef __attribute__((ext_vector_type(8))) _Float16 half8;
typedef __attribute__((ext_vector_type(4))) float f32x4;
typedef __attribute__((ext_vector_type(4))) int i32x4;

static __device__ __forceinline__ float fast_sigmoid(float v) {
    float e = __expf(-v);
    return __builtin_amdgcn_rcpf(1.0f + e);
}
static __device__ __forceinline__ float fast_tanh(float v) {
    return 2.0f * fast_sigmoid(2.0f * v) - 1.0f;
}

// ---------- prologue ----------

// dyn [T,N] fp32 -> dynT [N,T] fp16
__global__ __launch_bounds__(256)
void k_transpose(const float* __restrict__ dyn, half_t* __restrict__ dynT) {
    __shared__ float tile[64][65];
    int n0 = blockIdx.x * 64;
    int tx = threadIdx.x, ty = threadIdx.y;
#pragma unroll
    for (int r = 0; r < 16; ++r) {
        int t = r * 4 + ty;
        int n = n0 + tx;
        tile[t][tx] = (n < N_) ? dyn[(size_t)t * N_ + n] : 0.0f;
    }
    __syncthreads();
#pragma unroll
    for (int r = 0; r < 16; ++r) {
        int nl = r * 4 + ty;
        int n = n0 + nl;
        if (n < N_) dynT[(size_t)n * 64 + tx] = (half_t)tile[tx][nl];
    }
}

// per-(dst, src-tile) histogram
__global__ void k_hist(const int* __restrict__ src, const int* __restrict__ dst,
                       int* __restrict__ cnt) {
    int e = blockIdx.x * blockDim.x + threadIdx.x;
    if (e >= E_) return;
    atomicAdd(&cnt[dst[e] * 16 + (src[e] >> 12)], 1);
}

// deg from cnt + per-block inclusive scan
__global__ __launch_bounds__(256)
void k_scanA(const int* __restrict__ cnt, int* __restrict__ deg,
             int* __restrict__ row_ptr, int* __restrict__ bsum) {
    __shared__ int buf[256];
    int tid = threadIdx.x;
    int i = blockIdx.x * 256 + tid;
    int v = 0;
    if (i < N_) {
        const int4* c4 = (const int4*)(cnt + i * 16);
#pragma unroll
        for (int c = 0; c < 4; ++c) {
            int4 w = c4[c];
            v += w.x + w.y + w.z + w.w;
        }
        deg[i] = v;
    }
    buf[tid] = v;
    __syncthreads();
#pragma unroll
    for (int off = 1; off < 256; off <<= 1) {
        int t = (tid >= off) ? buf[tid - off] : 0;
        __syncthreads();
        buf[tid] += t;
        __syncthreads();
    }
    if (i < N_) row_ptr[i + 1] = buf[tid];
    if (tid == 255) bsum[blockIdx.x] = buf[255];
}
__global__ __launch_bounds__(256)
void k_scanB(int* __restrict__ bsum, int nb) {
    __shared__ int buf[256];
    int tid = threadIdx.x;
    buf[tid] = (tid < nb) ? bsum[tid] : 0;
    __syncthreads();
#pragma unroll
    for (int off = 1; off < 256; off <<= 1) {
        int t = (tid >= off) ? buf[tid - off] : 0;
        __syncthreads();
        buf[tid] += t;
        __syncthreads();
    }
    if (tid < nb) bsum[tid] = (tid > 0) ? buf[tid - 1] : 0;
}
__global__ __launch_bounds__(256)
void k_scanC(int* __restrict__ row_ptr, const int* __restrict__ bsum) {
    int i = blockIdx.x * 256 + threadIdx.x;
    if (i == 0) row_ptr[0] = 0;
    if (i < N_) row_ptr[i + 1] += bsum[blockIdx.x];
}

// rp2[n][t] = row_ptr[n] + prefix(cnt[n][0..t)); zero cnt (reused as cursor)
__global__ __launch_bounds__(256)
void k_rowscan(const int* __restrict__ row_ptr, int* __restrict__ cnt,
               int* __restrict__ rp2) {
    int n = blockIdx.x * 256 + threadIdx.x;
    if (n >= N_) return;
    int run = row_ptr[n];
#pragma unroll
    for (int t = 0; t < 16; ++t) {
        int c = cnt[n * 16 + t];
        rp2[n * 16 + t] = run;
        run += c;
        cnt[n * 16 + t] = 0;
    }
}

__global__ __launch_bounds__(256)
void k_node_init(const int* __restrict__ deg,
                 const float* __restrict__ statics,
                 const float* __restrict__ w0,
                 float* __restrict__ dinv,
                 float* __restrict__ selfn,
                 half_t* __restrict__ h0s) {          // [N,32] f16
    int n = blockIdx.x * blockDim.x + threadIdx.x;
    if (n >= N_) return;
    float d  = (float)deg[n] + 1.0f;
    float di = rsqrtf(d);
    dinv[n] = di;
    selfn[n] = di * di;
    float s[6];
#pragma unroll
    for (int j = 0; j < 6; ++j) s[j] = statics[n * 6 + j];
    half8 o[4];
#pragma unroll
    for (int k = 0; k < GH_; ++k) {
        float v = 0.0f;
#pragma unroll
        for (int j = 0; j < 6; ++j) v += s[j] * w0[(1 + j) * GH_ + k];
        o[k >> 3][k & 7] = (half_t)v;
    }
    half8* dst8 = (half8*)(h0s + (size_t)n * GH_);
#pragma unroll
    for (int c = 0; c < 4; ++c) dst8[c] = o[c];
}

// tile-ordered scatter: 8-byte record {src, norm}
__global__ void k_scatter2(const int* __restrict__ src, const int* __restrict__ dst,
                           const float* __restrict__ dinv,
                           const int* __restrict__ rp2, int* __restrict__ cnt,
                           int2* __restrict__ erec) {
    int e = blockIdx.x * blockDim.x + threadIdx.x;
    if (e >= E_) return;
    int s = src[e], d = dst[e];
    int slot = d * 16 + (s >> 12);
    int pos = rp2[slot] + atomicAdd(&cnt[slot], 1);
    erec[pos] = make_int2(s, __float_as_int(dinv[s] * dinv[d]));
}

// pre-swizzled GRU weight fragments, f16.
// layout: wB[(((c*12+nt)*4+q)*16+m)*8+j] = wT[k=c*32+q*8+j][col=nt*16+m]
__global__ void k_wB(const float* __restrict__ wih, const float* __restrict__ whh,
                     half_t* __restrict__ wB) {
    int idx = blockIdx.x * 256 + threadIdx.x;
    if (idx >= 96 * 192) return;
    int j = idx & 7;
    int r = idx >> 3;
    int m = r & 15; r >>= 4;
    int q = r & 3;  r >>= 2;
    int nt = r % 12;
    int c = r / 12;
    int k = c * 32 + q * 8 + j;
    int col = nt * 16 + m;
    float v = (k < 32) ? wih[col * 32 + k] : whh[col * 64 + (k - 32)];
    wB[idx] = (half_t)v;
}

// ---------- fused aall + csagg gather ----------

static __device__ __forceinline__
void aall_body(int bid, const int* __restrict__ row_ptr, const int2* __restrict__ erec,
               const float* __restrict__ selfn, const half_t* __restrict__ dynT,
               float* __restrict__ aT) {
    int gid = bid * 256 + threadIdx.x;
    int n = gid >> 6, lane = gid & 63;
    if (n >= N_) return;
    float acc = selfn[n] * (float)dynT[(size_t)n * 64 + lane];
    int e0 = row_ptr[n], e1 = row_ptr[n + 1];
    int e = e0;
    for (; e < e1 && (e & 3); ++e) {
        int2 r = erec[e];
        acc += __int_as_float(r.y) * (float)dynT[(size_t)r.x * 64 + lane];
    }
    for (; e + 4 <= e1; e += 4) {
        int4 p0 = *(const int4*)(erec + e);
        int4 p1 = *(const int4*)(erec + e + 2);
        float v0 = (float)dynT[(size_t)p0.x * 64 + lane];
        float v1 = (float)dynT[(size_t)p0.z * 64 + lane];
        float v2 = (float)dynT[(size_t)p1.x * 64 + lane];
        float v3 = (float)dynT[(size_t)p1.z * 64 + lane];
        acc += __int_as_float(p0.y) * v0 + __int_as_float(p0.w) * v1
             + __int_as_float(p1.y) * v2 + __int_as_float(p1.w) * v3;
    }
    for (; e < e1; ++e) {
        int2 r = erec[e];
        acc += __int_as_float(r.y) * (float)dynT[(size_t)r.x * 64 + lane];
    }
    aT[(size_t)n * 64 + lane] = acc;
}

static __device__ __forceinline__
void g16s_body(int bid, const int* __restrict__ row_ptr, const int2* __restrict__ erec,
               const float* __restrict__ selfn, const half_t* __restrict__ h0s,
               float* __restrict__ csagg) {
    int gid = bid * 256 + threadIdx.x;
    int n = gid >> 2, q = gid & 3;
    if (n >= N_) return;
    const half8* f8 = (const half8*)h0s;
    float acc[8];
    {
        half8 sv = f8[(size_t)n * 4 + q];
        float sn = selfn[n];
#pragma unroll
        for (int i = 0; i < 8; ++i) acc[i] = sn * (float)sv[i];
    }
    int e0 = row_ptr[n], e1 = row_ptr[n + 1];
    int e = e0;
    for (; e < e1 && (e & 3); ++e) {
        int2 r = erec[e];
        float nm = __int_as_float(r.y);
        half8 v = f8[(size_t)r.x * 4 + q];
#pragma unroll
        for (int i = 0; i < 8; ++i) acc[i] += nm * (float)v[i];
    }
    for (; e + 4 <= e1; e += 4) {
        int4 p0 = *(const int4*)(erec + e);
        int4 p1 = *(const int4*)(erec + e + 2);
        half8 v0 = f8[(size_t)p0.x * 4 + q];
        half8 v1 = f8[(size_t)p0.z * 4 + q];
        half8 v2 = f8[(size_t)p1.x * 4 + q];
        half8 v3 = f8[(size_t)p1.z * 4 + q];
        float n0 = __int_as_float(p0.y), n1 = __int_as_float(p0.w);
        float n2 = __int_as_float(p1.y), n3 = __int_as_float(p1.w);
#pragma unroll
        for (int i = 0; i < 8; ++i)
            acc[i] += n0 * (float)v0[i] + n1 * (float)v1[i]
                    + n2 * (float)v2[i] + n3 * (float)v3[i];
    }
    for (; e < e1; ++e) {
        int2 r = erec[e];
        float nm = __int_as_float(r.y);
        half8 v = f8[(size_t)r.x * 4 + q];
#pragma unroll
        for (int i = 0; i < 8; ++i) acc[i] += nm * (float)v[i];
    }
    float4* out = (float4*)(csagg + (size_t)n * GH_ + q * 8);
    out[0] = make_float4(acc[0], acc[1], acc[2], acc[3]);
    out[1] = make_float4(acc[4], acc[5], acc[6], acc[7]);
}

__global__ __launch_bounds__(256)
void k_aux(const int* __restrict__ row_ptr, const int2* __restrict__ erec,
           const float* __restrict__ selfn, const half_t* __restrict__ dynT,
           float* __restrict__ aT, const half_t* __restrict__ h0s,
           float* __restrict__ csagg) {
    if ((int)blockIdx.x < AB_)
        aall_body(blockIdx.x, row_ptr, erec, selfn, dynT, aT);
    else
        g16s_body((int)blockIdx.x - AB_, row_ptr, erec, selfn, h0s, csagg);
}

// ---------- per-pass ----------

// g1blk[n][u][32] f16 for u = 0..15 (t = tb+u)
static __device__ __forceinline__
void g1_body(int bid, int tb, const float* __restrict__ aT,
             const float* __restrict__ csagg, const float* __restrict__ w0,
             const float* __restrict__ b0, const float* __restrict__ w1,
             half_t* __restrict__ g1blk) {
    int n = bid * 256 + threadIdx.x;
    if (n >= N_) return;
    float c[GH_];
#pragma unroll
    for (int k = 0; k < GH_; ++k) c[k] = csagg[(size_t)n * GH_ + k] + b0[k];
    const float* at = aT + (size_t)n * 64 + tb;
    half8* outp = (half8*)(g1blk + (size_t)n * (TB_ * GH_));
#pragma unroll 1
    for (int u = 0; u < TB_; ++u) {
        float av = at[u];
        float h1[GH_];
#pragma unroll
        for (int k = 0; k < GH_; ++k) {
            float v = av * w0[k] + c[k];
            h1[k] = v > 0.0f ? v : 0.0f;
        }
        half8 o[4];
#pragma unroll
        for (int j = 0; j < GH_; ++j) {
            float v = 0.0f;
#pragma unroll
            for (int k = 0; k < GH_; ++k) v += h1[k] * w1[k * GH_ + j];
            o[j >> 3][j & 7] = (half_t)v;
        }
#pragma unroll
        for (int cc = 0; cc < 4; ++cc) outp[u * 4 + cc] = o[cc];
    }
}

__global__ __launch_bounds__(256)
void k_g1blk(const float* __restrict__ aT, const float* __restrict__ csagg,
             const float* __restrict__ w0, const float* __restrict__ b0,
             const float* __restrict__ w1, half_t* __restrict__ g1blk, int tb) {
    g1_body(blockIdx.x, tb, aT, csagg, w0, b0, w1, g1blk);
}

// gather 16 timesteps: 16 lanes/node; 1KB contiguous per edge (tile-sorted CSR).
// nt stores for xblk (don't evict g1blk from L2); nt loads for streamed erec.
__global__ __launch_bounds__(256)
void k_gatherx(const int* __restrict__ row_ptr, const int2* __restrict__ erec,
               const float* __restrict__ selfn, const half_t* __restrict__ g1blk,
               const float* __restrict__ b1, half_t* __restrict__ xblk) {
    int gid = blockIdx.x * 256 + threadIdx.x;
    int n = gid >> 4, q = gid & 15;
    if (n >= N_) return;
    const half8* g8 = (const half8*)g1blk;   // node row = 64 chunks of 16B
    float acc[4][8];
    {
        float sn = selfn[n];
#pragma unroll
        for (int u = 0; u < 4; ++u) {
            half8 sv = g8[(size_t)n * 64 + q + 16 * u];
#pragma unroll
            for (int i = 0; i < 8; ++i) acc[u][i] = sn * (float)sv[i];
        }
    }
    int e0 = row_ptr[n], e1 = row_ptr[n + 1];
    int e = e0;
    for (; e < e1 && (e & 3); ++e) {
        int2 r = erec[e];
        float nm = __int_as_float(r.y);
        size_t base = (size_t)r.x * 64 + q;
#pragma unroll
        for (int u = 0; u < 4; ++u) {
            half8 v = g8[base + 16 * u];
#pragma unroll
            for (int i = 0; i < 8; ++i) acc[u][i] += nm * (float)v[i];
        }
    }
    for (; e + 4 <= e1; e += 4) {
        i32x4 p0 = __builtin_nontemporal_load((const i32x4*)(erec + e));
        i32x4 p1 = __builtin_nontemporal_load((const i32x4*)(erec + e + 2));
        size_t b0a = (size_t)p0[0] * 64 + q;
        size_t b1a = (size_t)p0[2] * 64 + q;
        size_t b2a = (size_t)p1[0] * 64 + q;
        size_t b3a = (size_t)p1[2] * 64 + q;
        float n0 = __int_as_float(p0[1]), n1 = __int_as_float(p0[3]);
        float n2 = __int_as_float(p1[1]), n3 = __int_as_float(p1[3]);
        half8 v0[4], v1[4], v2[4], v3[4];
#pragma unroll
        for (int u = 0; u < 4; ++u) {
            v0[u] = g8[b0a + 16 * u];
            v1[u] = g8[b1a + 16 * u];
            v2[u] = g8[b2a + 16 * u];
            v3[u] = g8[b3a + 16 * u];
        }
#pragma unroll
        for (int u = 0; u < 4; ++u)
#pragma unroll
            for (int i = 0; i < 8; ++i)
                acc[u][i] += n0 * (float)v0[u][i] + n1 * (float)v1[u][i]
                           + n2 * (float)v2[u][i] + n3 * (float)v3[u][i];
    }
    for (; e < e1; ++e) {
        int2 r = erec[e];
        float nm = __int_as_float(r.y);
        size_t base = (size_t)r.x * 64 + q;
#pragma unroll
        for (int u = 0; u < 4; ++u) {
            half8 v = g8[base + 16 * u];
#pragma unroll
            for (int i = 0; i < 8; ++i) acc[u][i] += nm * (float)v[i];
        }
    }
    int kc = (q & 3) * 8;
    const float* bb = b1 + kc;
#pragma unroll
    for (int u = 0; u < 4; ++u) {
        int t = (q >> 2) + 4 * u;
        half8 o;
#pragma unroll
        for (int i = 0; i < 8; ++i)
            o[i] = (half_t)fmaxf(acc[u][i] + bb[i], 0.0f);
        __builtin_nontemporal_store(o, (half8*)(xblk + ((size_t)t * N_ + n) * GH_ + kc));
    }
}

// ---------- fused MFMA GRU (pass p) + g1 (pass p+1) ----------
#define HSTR_ 72
__global__ __launch_bounds__(256, 2)
void k_gru_g1(const half_t* __restrict__ xblk,   // [TB][N][32] f16
              const half_t* __restrict__ wB,     // swizzled fragments
              const float* __restrict__ bih, const float* __restrict__ bhh,
              half_t* __restrict__ hA,           // [Npad][64] f16
              const float* __restrict__ aT, const float* __restrict__ csagg,
              const float* __restrict__ w0, const float* __restrict__ b0,
              const float* __restrict__ w1, half_t* __restrict__ g1blk,
              int tb_next, int do_g1) {
    __shared__ half_t hL[64 * HSTR_];
    if ((int)blockIdx.x >= GB_) {
        if (do_g1)
            g1_body((int)blockIdx.x - GB_, tb_next, aT, csagg, w0, b0, w1, g1blk);
        return;
    }
    int tid = threadIdx.x;
    int nb0 = blockIdx.x * 64;
    for (int i = tid; i < 64 * 8; i += 256) {
        int node = i >> 3, ch = i & 7;
        half8 v = *(const half8*)(hA + (size_t)(nb0 + node) * RH_ + ch * 8);
        *(half8*)(hL + node * HSTR_ + ch * 8) = v;
    }
    __syncthreads();
    int lane = tid & 63;
    int wv = tid >> 6;
    int c16 = lane & 15, q = lane >> 4;
    const half8* wB8 = (const half8*)wB;
    half8 bfr[3][12];
#pragma unroll
    for (int c = 0; c < 3; ++c)
#pragma unroll
        for (int nt = 0; nt < 12; ++nt)
            bfr[c][nt] = wB8[((c * 12 + nt) * 4 + q) * 16 + c16];
    float br[4], bz[4], bnx[4], bnh[4];
#pragma unroll
    for (int jt = 0; jt < 4; ++jt) {
        int j = jt * 16 + c16;
        br[jt]  = bih[j] + bhh[j];
        bz[jt]  = bih[64 + j] + bhh[64 + j];
        bnx[jt] = bih[128 + j];
        bnh[jt] = bhh[128 + j];
    }
    int mrow = wv * 16 + c16;
    const half_t* hrow = hL + mrow * HSTR_;
    const f32x4 zero = {0.0f, 0.0f, 0.0f, 0.0f};
#pragma unroll 1
    for (int u = 0; u < TB_; ++u) {
        half8 ax = __builtin_nontemporal_load(
            (const half8*)(xblk + ((size_t)u * N_ + nb0 + mrow) * GH_ + q * 8));
        half8 ah0 = *(const half8*)(hrow + q * 8);
        half8 ah1 = *(const half8*)(hrow + 32 + q * 8);
        f32x4 Crz[8], Cnx[4], Cnh[4];
#pragma unroll
        for (int nt = 0; nt < 8; ++nt) {
            Crz[nt] = __builtin_amdgcn_mfma_f32_16x16x32_f16(ax,  bfr[0][nt], zero,     0, 0, 0);
            Crz[nt] = __builtin_amdgcn_mfma_f32_16x16x32_f16(ah0, bfr[1][nt], Crz[nt], 0, 0, 0);
            Crz[nt] = __builtin_amdgcn_mfma_f32_16x16x32_f16(ah1, bfr[2][nt], Crz[nt], 0, 0, 0);
        }
#pragma unroll
        for (int nt = 0; nt < 4; ++nt) {
            Cnx[nt] = __builtin_amdgcn_mfma_f32_16x16x32_f16(ax,  bfr[0][8 + nt], zero,     0, 0, 0);
            Cnh[nt] = __builtin_amdgcn_mfma_f32_16x16x32_f16(ah0, bfr[1][8 + nt], zero,     0, 0, 0);
            Cnh[nt] = __builtin_amdgcn_mfma_f32_16x16x32_f16(ah1, bfr[2][8 + nt], Cnh[nt], 0, 0, 0);
        }
#pragma unroll
        for (int jt = 0; jt < 4; ++jt) {
#pragma unroll
            for (int reg = 0; reg < 4; ++reg) {
                int nl = wv * 16 + q * 4 + reg;
                int jj = jt * 16 + c16;
                float hold = (float)hL[nl * HSTR_ + jj];
                float r  = fast_sigmoid(Crz[jt][reg] + br[jt]);
                float z  = fast_sigmoid(Crz[4 + jt][reg] + bz[jt]);
                float cd = fast_tanh(Cnx[jt][reg] + bnx[jt] + r * (Cnh[jt][reg] + bnh[jt]));
                hL[nl * HSTR_ + jj] = (half_t)((1.0f - z) * cd + z * hold);
            }
        }
    }
    __syncthreads();
    for (int i = tid; i < 64 * 8; i += 256) {
        int node = i >> 3, ch = i & 7;
        half8 v = *(const half8*)(hL + node * HSTR_ + ch * 8);
        *(half8*)(hA + (size_t)(nb0 + node) * RH_ + ch * 8) = v;
    }
}

__global__ __launch_bounds__(256)
void k_mlp(const half_t* __restrict__ hA, const float* __restrict__ w1,
           const float* __restrict__ b1, const float* __restrict__ w2,
           const float* __restrict__ b2, float* __restrict__ out) {
    int n = blockIdx.x * blockDim.x + threadIdx.x;
    if (n >= N_) return;
    float h[RH_];
    const half8* h8 = (const half8*)(hA + (size_t)n * RH_);
#pragma unroll
    for (int c = 0; c < 8; ++c) {
        half8 v = h8[c];
#pragma unroll
        for (int i = 0; i < 8; ++i) h[c * 8 + i] = (float)v[i];
    }
    float acc = b2[0];
#pragma unroll 1
    for (int j = 0; j < RH_; ++j) {
        float v = b1[j];
#pragma unroll
        for (int k = 0; k < RH_; ++k) v += w1[j * RH_ + k] * h[k];
        v = v > 0.0f ? v : 0.0f;
        acc += w2[j] * v;
    }
    out[n] = acc;
}

extern "C" void kernel_launch(void* const* d_in, const int* in_sizes, int n_in,
                              void* d_out, int out_size, void* d_ws, size_t ws_size,
                              hipStream_t stream) {
    const float* dyn     = (const float*)d_in[0];
    const float* statics = (const float*)d_in[1];
    const int*   ei      = (const int*)d_in[2];
    const float* w0      = (const float*)d_in[3];
    const float* b0      = (const float*)d_in[4];
    const float* w1      = (const float*)d_in[5];
    const float* b1      = (const float*)d_in[6];
    const float* wih     = (const float*)d_in[7];
    const float* whh     = (const float*)d_in[8];
    const float* bih     = (const float*)d_in[9];
    const float* bhh     = (const float*)d_in[10];
    const float* mw1     = (const float*)d_in[11];
    const float* mb1     = (const float*)d_in[12];
    const float* mw2     = (const float*)d_in[13];
    const float* mb2     = (const float*)d_in[14];
    const int* src = ei;
    const int* dst = ei + E_;

    char* ws = (char*)d_ws;
    auto alloc = [&](size_t elems) {        // 4B units, 256B-aligned
        elems = (elems + 63) & ~(size_t)63;
        void* p = ws; ws += elems * 4; return p;
    };
    const int NPAD = N_ + 64;
    int*    deg     = (int*)alloc(N_);
    int*    row_ptr = (int*)alloc(N_ + 4);
    int*    bsum    = (int*)alloc(256);
    int*    cnt     = (int*)alloc((size_t)N_ * 16);
    int*    rp2     = (int*)alloc((size_t)N_ * 16);
    int2*   erec    = (int2*)alloc((size_t)E_ * 2);
    float*  dinv    = (float*)alloc(N_);
    float*  selfn   = (float*)alloc(N_);
    half_t* h0s     = (half_t*)alloc((size_t)N_ * GH_ / 2);        // f16 [N,32]
    float*  csagg   = (float*)alloc(32 * N_);
    half_t* g1blk   = (half_t*)alloc((size_t)N_ * TB_ * GH_ / 2);  // f16 [N][16][32]
    half_t* xblk    = (half_t*)alloc(((size_t)TB_ * N_ + 64) * GH_ / 2); // f16 [16][N][32]
    half_t* hA      = (half_t*)alloc((size_t)NPAD * RH_ / 2);      // f16 [Npad][64]
    half_t* dynT    = (half_t*)alloc((size_t)N_ * 64 / 2);         // f16 [N][64]
    float*  aT      = (float*)alloc(64 * N_);
    half_t* wB      = (half_t*)alloc(96 * 192 / 2);

    auto cdiv = [](long long x, int b) { return (unsigned)((x + b - 1) / b); };
    const int B = 256;

    hipMemsetAsync(cnt, 0, (size_t)N_ * 16 * sizeof(int), stream);
    hipMemsetAsync(hA, 0, (size_t)NPAD * RH_ * sizeof(half_t), stream);

    k_transpose<<<cdiv(N_, 64), dim3(64, 4), 0, stream>>>(dyn, dynT);
    k_hist<<<cdiv(E_, B), B, 0, stream>>>(src, dst, cnt);
    k_scanA<<<NB_, B, 0, stream>>>(cnt, deg, row_ptr, bsum);
    k_scanB<<<1, B, 0, stream>>>(bsum, NB_);
    k_scanC<<<NB_, B, 0, stream>>>(row_ptr, bsum);
    k_rowscan<<<NB_, B, 0, stream>>>(row_ptr, cnt, rp2);
    k_node_init<<<NB_, B, 0, stream>>>(deg, statics, w0, dinv, selfn, h0s);
    k_scatter2<<<cdiv(E_, B), B, 0, stream>>>(src, dst, dinv, rp2, cnt, erec);
    k_wB<<<cdiv(96 * 192, B), B, 0, stream>>>(wih, whh, wB);
    k_aux<<<AB_ + GB_, B, 0, stream>>>(row_ptr, erec, selfn, dynT, aT, h0s, csagg);

    k_g1blk<<<NB_, B, 0, stream>>>(aT, csagg, w0, b0, w1, g1blk, 0);
    for (int p = 0; p < NP_; ++p) {
        k_gatherx<<<XB_, B, 0, stream>>>(row_ptr, erec, selfn, g1blk, b1, xblk);
        int do_g1 = (p + 1 < NP_) ? 1 : 0;
        unsigned grid = GB_ + (do_g1 ? NB_ : 0);
        k_gru_g1<<<grid, B, 0, stream>>>(xblk, wB, bih, bhh, hA,
                                         aT, csagg, w0, b0, w1, g1blk,
                                         (p + 1) * TB_, do_g1);
    }
    k_mlp<<<NB_, B, 0, stream>>>(hA, mw1, mb1, mw2, mb2, (float*)d_out);
}